// Round 1
// baseline (387.935 us; speedup 1.0000x reference)
//
#include <hip/hip_runtime.h>
#include <hip/hip_bf16.h>

#define DH 128

static constexpr float TEMP_ = 10.0f;
static constexpr float LN_EPS_ = 1e-5f;

// ---------------- CSR build ----------------

__global__ void k_zero_cnt(int* cnt_d, int* cnt_s, int n) {
  int i = blockIdx.x * blockDim.x + threadIdx.x;
  if (i < n) { cnt_d[i] = 0; cnt_s[i] = 0; }
}

__global__ void k_hist(const int* __restrict__ ei, int E, int* cnt_d, int* cnt_s) {
  int e = blockIdx.x * blockDim.x + threadIdx.x;
  if (e < E) {
    atomicAdd(&cnt_s[ei[e]], 1);       // src = ei[0][e]
    atomicAdd(&cnt_d[ei[E + e]], 1);   // dst = ei[1][e]
  }
}

// Single block, 1024 threads; scans both count arrays, derives dinv (GCN,
// in-degree+self-loop) and dego (entropy A row-sum = out-degree), zeroes
// counts for reuse as fill cursors.
__global__ __launch_bounds__(1024) void k_scan(int* cnt_d, int* cnt_s,
                                               int* off_d, int* off_s,
                                               float* dinv, float* dego, int n) {
  __shared__ int sm[1024];
  const int t = threadIdx.x;
  for (int pass = 0; pass < 2; ++pass) {
    int* cnt = pass ? cnt_s : cnt_d;
    int* off = pass ? off_s : off_d;
    const int base = t * 8;
    int lc[8]; int s = 0;
    #pragma unroll
    for (int j = 0; j < 8; ++j) {
      int idx = base + j;
      int v = (idx < n) ? cnt[idx] : 0;
      lc[j] = v; s += v;
    }
    sm[t] = s; __syncthreads();
    for (int o = 1; o < 1024; o <<= 1) {
      int v = (t >= o) ? sm[t - o] : 0;
      __syncthreads();
      sm[t] += v;
      __syncthreads();
    }
    int run = sm[t] - s;         // exclusive prefix
    int total = sm[1023];
    #pragma unroll
    for (int j = 0; j < 8; ++j) {
      int idx = base + j;
      if (idx < n) {
        off[idx] = run; run += lc[j];
        if (pass == 0) dinv[idx] = rsqrtf((float)lc[j] + 1.0f);
        else           dego[idx] = (float)lc[j];
        cnt[idx] = 0;            // cursor for fill
      }
    }
    if (t == 0) off[n] = total;
    __syncthreads();
  }
}

__global__ void k_fill(const int* __restrict__ ei, int E,
                       const int* __restrict__ off_d, const int* __restrict__ off_s,
                       int* cnt_d, int* cnt_s, int* idx_d, int* idx_s) {
  int e = blockIdx.x * blockDim.x + threadIdx.x;
  if (e < E) {
    int s = ei[e], d = ei[E + e];
    int p = atomicAdd(&cnt_d[d], 1);
    idx_d[off_d[d] + p] = s;     // in-edges of d store src
    int q = atomicAdd(&cnt_s[s], 1);
    idx_s[off_s[s] + q] = d;     // out-edges of s store dst
  }
}

// ---------------- GEMM: H[n,DOUT] = X[n,128] @ W[128,DOUT] ----------------
template <int DOUT>
__global__ __launch_bounds__(256) void k_gemm(const float* __restrict__ X,
                                              const float* __restrict__ W,
                                              float* __restrict__ H) {
  __shared__ float Ws[64 * DOUT];     // one 64-row k-tile of W
  __shared__ float xs[16 * 128];      // 16 rows of X
  const int t = threadIdx.x;
  const int row0 = blockIdx.x * 16;

  const float4* xg = (const float4*)(X + row0 * 128);
  float4* xs4 = (float4*)xs;
  xs4[t] = xg[t];
  xs4[t + 256] = xg[t + 256];

  constexpr int RPT = (16 * DOUT) / 256;   // rows per thread
  const int c = t % DOUT;
  const int rg = t / DOUT;
  float acc[RPT];
  #pragma unroll
  for (int r = 0; r < RPT; ++r) acc[r] = 0.f;

  for (int kt = 0; kt < 2; ++kt) {
    __syncthreads();
    for (int i = t; i < 64 * DOUT; i += 256) Ws[i] = W[kt * 64 * DOUT + i];
    __syncthreads();
    for (int k = 0; k < 64; ++k) {
      float wv = Ws[k * DOUT + c];
      #pragma unroll
      for (int r = 0; r < RPT; ++r)
        acc[r] += xs[(rg * RPT + r) * 128 + kt * 64 + k] * wv;
    }
  }
  #pragma unroll
  for (int r = 0; r < RPT; ++r)
    H[(row0 + rg * RPT + r) * DOUT + c] = acc[r];
}

// ---------------- reductions ----------------
__device__ __forceinline__ float wave_reduce(float v) {
  #pragma unroll
  for (int o = 32; o > 0; o >>= 1) v += __shfl_down(v, o, 64);
  return v;
}
__device__ __forceinline__ float block_reduce_128(float v, float* sm2) {
  v = wave_reduce(v);
  if ((threadIdx.x & 63) == 0) sm2[threadIdx.x >> 6] = v;
  __syncthreads();
  float r = sm2[0] + sm2[1];
  __syncthreads();
  return r;
}

// ---------------- GCN conv aggregate (+bias, +self loop) and row norms ----
__global__ __launch_bounds__(128) void k_conv_agg(const float* __restrict__ H,
                                                  const float* __restrict__ dinv,
                                                  const float* __restrict__ b,
                                                  const int* __restrict__ off_d,
                                                  const int* __restrict__ idx_d,
                                                  float* __restrict__ G,
                                                  float* __restrict__ sq) {
  __shared__ float sm2[2];
  const int i = blockIdx.x, f = threadIdx.x;
  const float di = dinv[i];
  float acc = di * H[i * DH + f];                     // self loop (dinv_i^2 * h_i)
  const int oe = off_d[i + 1];
  for (int o = off_d[i]; o < oe; ++o) {
    int s = idx_d[o];
    acc += dinv[s] * H[s * DH + f];
  }
  float gi = b[f] + di * acc;
  G[i * DH + f] = gi;
  float s2 = block_reduce_128(gi * gi, sm2);
  if (f == 0) sq[i] = s2;
}

// ---------------- Ax = A@G (CSR_src), Asq, En ----------------
__global__ __launch_bounds__(128) void k_ax_en(const float* __restrict__ G,
                                               const float* __restrict__ sq,
                                               const float* __restrict__ dego,
                                               const int* __restrict__ off_s,
                                               const int* __restrict__ idx_s,
                                               float* __restrict__ Ax,
                                               float* __restrict__ En) {
  __shared__ float sm2[2];
  const int i = blockIdx.x, f = threadIdx.x;
  float axf = 0.f, asq = 0.f;
  const int oe = off_s[i + 1];
  for (int o = off_s[i]; o < oe; ++o) {
    int d = idx_s[o];
    axf += G[d * DH + f];
    asq += sq[d];                 // redundant across lanes, same value each
  }
  Ax[i * DH + f] = axf;
  float dot = block_reduce_128(G[i * DH + f] * axf, sm2);
  if (f == 0) En[i] = 0.5f * (dego[i] * sq[i] + asq - 2.f * dot);
}

// ---------------- softmax over entropies -> c ----------------
__device__ __forceinline__ float red1024(float v, bool domax, float* sm) {
  #pragma unroll
  for (int o = 32; o > 0; o >>= 1) {
    float u = __shfl_down(v, o, 64);
    v = domax ? fmaxf(v, u) : v + u;
  }
  if ((threadIdx.x & 63) == 0) sm[threadIdx.x >> 6] = v;
  __syncthreads();
  if (threadIdx.x == 0) {
    float r = sm[0];
    for (int k = 1; k < 16; ++k) r = domax ? fmaxf(r, sm[k]) : r + sm[k];
    sm[0] = r;
  }
  __syncthreads();
  float r = sm[0];
  __syncthreads();
  return r;
}

__global__ __launch_bounds__(1024) void k_softc(const float* __restrict__ En,
                                                float* __restrict__ c, int n) {
  __shared__ float sm[16];
  const int t = threadIdx.x;
  float m = -1e30f;
  for (int i = t; i < n; i += 1024) m = fmaxf(m, En[i]);
  m = red1024(m, true, sm);
  const float denom = (m + 1e-12f) * TEMP_;
  float se = 0.f;
  for (int i = t; i < n; i += 1024) se += expf(-En[i] / denom);
  se = red1024(se, false, sm);
  const float logZ = logf(se);
  float Sacc = 0.f;
  for (int i = t; i < n; i += 1024) {
    float li = -En[i] / denom;
    float P = expf(li) / se;
    Sacc -= P * (li - logZ);
  }
  float S = red1024(Sacc, false, sm);
  for (int i = t; i < n; i += 1024) {
    float li = -En[i] / denom;
    float P = expf(li) / se;
    c[i] = P * ((li - logZ) + S) / TEMP_;
  }
}

// ---------------- A^T c, A^T(c*g), eg, relu, layernorm ----------------
__global__ __launch_bounds__(128) void k_combine_ln(const float* __restrict__ G,
                                                    const float* __restrict__ Ax,
                                                    const float* __restrict__ cvec,
                                                    const float* __restrict__ dego,
                                                    const int* __restrict__ off_d,
                                                    const int* __restrict__ idx_d,
                                                    const float* __restrict__ gamma,
                                                    const float* __restrict__ beta,
                                                    float* __restrict__ Xout) {
  __shared__ float sm2[2];
  const int i = blockIdx.x, f = threadIdx.x;
  const float gi = G[i * DH + f];
  float tf = 0.f, atc = 0.f;
  const int oe = off_d[i + 1];
  for (int o = off_d[i]; o < oe; ++o) {
    int s = idx_d[o];
    float cs = cvec[s];
    atc += cs;                    // redundant per lane, same value
    tf += cs * G[s * DH + f];
  }
  float eg = cvec[i] * (dego[i] * gi - Ax[i * DH + f]) + atc * gi - tf;
  float v = fmaxf(gi + eg, 0.f);
  float mu = block_reduce_128(v, sm2) * (1.f / 128.f);
  float dv = v - mu;
  float var = block_reduce_128(dv * dv, sm2) * (1.f / 128.f);
  Xout[i * DH + f] = dv * rsqrtf(var + LN_EPS_) * gamma[f] + beta[f];
}

// ---------------- final conv aggregate (DOUT=64) ----------------
__global__ __launch_bounds__(64) void k_final_agg(const float* __restrict__ H,
                                                  const float* __restrict__ dinv,
                                                  const float* __restrict__ bout,
                                                  const int* __restrict__ off_d,
                                                  const int* __restrict__ idx_d,
                                                  float* __restrict__ out) {
  const int i = blockIdx.x, f = threadIdx.x;
  const float di = dinv[i];
  float acc = di * H[i * 64 + f];
  const int oe = off_d[i + 1];
  for (int o = off_d[i]; o < oe; ++o) {
    int s = idx_d[o];
    acc += dinv[s] * H[s * 64 + f];
  }
  out[i * 64 + f] = bout[f] + di * acc;
}

extern "C" void kernel_launch(void* const* d_in, const int* in_sizes, int n_in,
                              void* d_out, int out_size, void* d_ws, size_t ws_size,
                              hipStream_t stream) {
  const float* x    = (const float*)d_in[0];
  const int*   ei   = (const int*)d_in[1];
  const float* W1   = (const float*)d_in[2];
  const float* b1   = (const float*)d_in[3];
  const float* W2   = (const float*)d_in[4];
  const float* b2   = (const float*)d_in[5];
  const float* Wout = (const float*)d_in[6];
  const float* bout = (const float*)d_in[7];
  const float* gam  = (const float*)d_in[8];
  const float* bet  = (const float*)d_in[9];
  float* out = (float*)d_out;

  const int N = in_sizes[0] / DH;   // 8000
  const int E = in_sizes[1] / 2;    // 256000

  float* ws = (float*)d_ws;
  float* xf = ws;   ws += N * DH;
  float* h0 = ws;   ws += N * DH;
  float* G  = ws;   ws += N * DH;
  float* Ax = ws;   ws += N * DH;
  float* sq = ws;   ws += N;
  float* En = ws;   ws += N;
  float* cv = ws;   ws += N;
  float* dinv = ws; ws += N;
  float* dego = ws; ws += N;
  int* cnt_d = (int*)ws; ws += N;
  int* cnt_s = (int*)ws; ws += N;
  int* off_d = (int*)ws; ws += N + 4;
  int* off_s = (int*)ws; ws += N + 4;
  int* idx_d = (int*)ws; ws += E;
  int* idx_s = (int*)ws; ws += E;

  k_zero_cnt<<<(N + 255) / 256, 256, 0, stream>>>(cnt_d, cnt_s, N);
  k_hist<<<(E + 255) / 256, 256, 0, stream>>>(ei, E, cnt_d, cnt_s);
  k_scan<<<1, 1024, 0, stream>>>(cnt_d, cnt_s, off_d, off_s, dinv, dego, N);
  k_fill<<<(E + 255) / 256, 256, 0, stream>>>(ei, E, off_d, off_s, cnt_d, cnt_s,
                                              idx_d, idx_s);

  const float* xin = x;
  const float* Wl[2] = {W1, W2};
  const float* bl[2] = {b1, b2};
  for (int l = 0; l < 2; ++l) {
    k_gemm<DH><<<N / 16, 256, 0, stream>>>(xin, Wl[l], h0);
    k_conv_agg<<<N, 128, 0, stream>>>(h0, dinv, bl[l], off_d, idx_d, G, sq);
    k_ax_en<<<N, 128, 0, stream>>>(G, sq, dego, off_s, idx_s, Ax, En);
    k_softc<<<1, 1024, 0, stream>>>(En, cv, N);
    k_combine_ln<<<N, 128, 0, stream>>>(G, Ax, cv, dego, off_d, idx_d, gam, bet, xf);
    xin = xf;
  }
  k_gemm<64><<<N / 16, 256, 0, stream>>>(xf, Wout, h0);
  k_final_agg<<<N, 64, 0, stream>>>(h0, dinv, bout, off_d, idx_d, out);
}

// Round 2
// 299.824 us; speedup vs baseline: 1.2939x; 1.2939x over previous
//
#include <hip/hip_runtime.h>
#include <hip/hip_bf16.h>

#define DH 128

static constexpr float TEMP_ = 10.0f;
static constexpr float LN_EPS_ = 1e-5f;

// ---------------- float4 helpers ----------------
__device__ __forceinline__ float4 f4_fma(float a, float4 x, float4 y) {
  y.x = fmaf(a, x.x, y.x); y.y = fmaf(a, x.y, y.y);
  y.z = fmaf(a, x.z, y.z); y.w = fmaf(a, x.w, y.w);
  return y;
}
__device__ __forceinline__ float4 f4_add(float4 a, float4 b) {
  a.x += b.x; a.y += b.y; a.z += b.z; a.w += b.w; return a;
}
__device__ __forceinline__ float f4_hsum(float4 a) { return (a.x + a.y) + (a.z + a.w); }

__device__ __forceinline__ float grp_sum32(float v) {
  #pragma unroll
  for (int o = 16; o > 0; o >>= 1) v += __shfl_down(v, o, 32);
  return __shfl(v, 0, 32);
}

// ---------------- CSR build ----------------
__global__ void k_hist(const int* __restrict__ ei, int E, int* cnt_d, int* cnt_s) {
  int e = blockIdx.x * blockDim.x + threadIdx.x;
  if (e < E) {
    atomicAdd(&cnt_s[ei[e]], 1);       // src = ei[0][e]
    atomicAdd(&cnt_d[ei[E + e]], 1);   // dst = ei[1][e]
  }
}

__global__ __launch_bounds__(1024) void k_scan(int* cnt_d, int* cnt_s,
                                               int* off_d, int* off_s,
                                               float* dinv, float* dego, int n) {
  __shared__ int sm[1024];
  const int t = threadIdx.x;
  for (int pass = 0; pass < 2; ++pass) {
    int* cnt = pass ? cnt_s : cnt_d;
    int* off = pass ? off_s : off_d;
    const int base = t * 8;
    int lc[8]; int s = 0;
    #pragma unroll
    for (int j = 0; j < 8; ++j) {
      int idx = base + j;
      int v = (idx < n) ? cnt[idx] : 0;
      lc[j] = v; s += v;
    }
    sm[t] = s; __syncthreads();
    for (int o = 1; o < 1024; o <<= 1) {
      int v = (t >= o) ? sm[t - o] : 0;
      __syncthreads();
      sm[t] += v;
      __syncthreads();
    }
    int run = sm[t] - s;
    int total = sm[1023];
    #pragma unroll
    for (int j = 0; j < 8; ++j) {
      int idx = base + j;
      if (idx < n) {
        off[idx] = run; run += lc[j];
        if (pass == 0) dinv[idx] = rsqrtf((float)lc[j] + 1.0f);
        else           dego[idx] = (float)lc[j];
        cnt[idx] = 0;
      }
    }
    if (t == 0) off[n] = total;
    __syncthreads();
  }
}

__global__ void k_fill(const int* __restrict__ ei, int E,
                       const int* __restrict__ off_d, const int* __restrict__ off_s,
                       int* cnt_d, int* cnt_s, int* idx_d, int* idx_s) {
  int e = blockIdx.x * blockDim.x + threadIdx.x;
  if (e < E) {
    int s = ei[e], d = ei[E + e];
    int p = atomicAdd(&cnt_d[d], 1);
    idx_d[off_d[d] + p] = s;
    int q = atomicAdd(&cnt_s[s], 1);
    idx_s[off_s[s] + q] = d;
  }
}

// ---------------- GEMM: H[n,DOUT] = X[n,128] @ W[128,DOUT] ----------------
template <int DOUT>
__global__ __launch_bounds__(256) void k_gemm(const float* __restrict__ X,
                                              const float* __restrict__ W,
                                              float* __restrict__ H) {
  __shared__ float Ws[64 * DOUT];
  __shared__ float xs[16 * 128];
  const int t = threadIdx.x;
  const int row0 = blockIdx.x * 16;

  const float4* xg = (const float4*)(X + row0 * 128);
  float4* xs4 = (float4*)xs;
  xs4[t] = xg[t];
  xs4[t + 256] = xg[t + 256];

  constexpr int RPT = (16 * DOUT) / 256;
  const int c = t % DOUT;
  const int rg = t / DOUT;
  float acc[RPT];
  #pragma unroll
  for (int r = 0; r < RPT; ++r) acc[r] = 0.f;

  for (int kt = 0; kt < 2; ++kt) {
    __syncthreads();
    for (int i = t; i < 64 * DOUT; i += 256) Ws[i] = W[kt * 64 * DOUT + i];
    __syncthreads();
    for (int k = 0; k < 64; ++k) {
      float wv = Ws[k * DOUT + c];
      #pragma unroll
      for (int r = 0; r < RPT; ++r)
        acc[r] += xs[(rg * RPT + r) * 128 + kt * 64 + k] * wv;
    }
  }
  #pragma unroll
  for (int r = 0; r < RPT; ++r)
    H[(row0 + rg * RPT + r) * DOUT + c] = acc[r];
}

// ---------------- conv aggregate: 32 lanes/node, float4/lane ----------------
// grid: N/8 blocks of 256. Group g = t/32 handles node blockIdx.x*8+g.
__global__ __launch_bounds__(256) void k_conv_agg(const float* __restrict__ H,
                                                  const float* __restrict__ dinv,
                                                  const float* __restrict__ b,
                                                  const int* __restrict__ off_d,
                                                  const int* __restrict__ idx_d,
                                                  float* __restrict__ G,
                                                  float* __restrict__ sq) {
  const int lane = threadIdx.x & 31;
  const int i = blockIdx.x * 8 + (threadIdx.x >> 5);
  const float4* Hv = (const float4*)H;
  const float di = dinv[i];
  float4 acc = Hv[i * 32 + lane];
  acc.x *= di; acc.y *= di; acc.z *= di; acc.w *= di;   // self loop
  int o = off_d[i];
  const int oe = off_d[i + 1];
  for (; o + 4 <= oe; o += 4) {
    int s0 = idx_d[o], s1 = idx_d[o + 1], s2 = idx_d[o + 2], s3 = idx_d[o + 3];
    float4 r0 = Hv[s0 * 32 + lane], r1 = Hv[s1 * 32 + lane];
    float4 r2 = Hv[s2 * 32 + lane], r3 = Hv[s3 * 32 + lane];
    float d0 = dinv[s0], d1 = dinv[s1], d2 = dinv[s2], d3 = dinv[s3];
    acc = f4_fma(d0, r0, acc); acc = f4_fma(d1, r1, acc);
    acc = f4_fma(d2, r2, acc); acc = f4_fma(d3, r3, acc);
  }
  for (; o < oe; ++o) {
    int s = idx_d[o];
    acc = f4_fma(dinv[s], Hv[s * 32 + lane], acc);
  }
  float4 bb = ((const float4*)b)[lane];
  float4 gi;
  gi.x = fmaf(di, acc.x, bb.x); gi.y = fmaf(di, acc.y, bb.y);
  gi.z = fmaf(di, acc.z, bb.z); gi.w = fmaf(di, acc.w, bb.w);
  ((float4*)G)[i * 32 + lane] = gi;
  float s2 = grp_sum32(gi.x * gi.x + gi.y * gi.y + gi.z * gi.z + gi.w * gi.w);
  if (lane == 0) sq[i] = s2;
}

// ---------------- Ax = A@G (CSR_src), Asq, En ----------------
__global__ __launch_bounds__(256) void k_ax_en(const float* __restrict__ G,
                                               const float* __restrict__ sq,
                                               const float* __restrict__ dego,
                                               const int* __restrict__ off_s,
                                               const int* __restrict__ idx_s,
                                               float* __restrict__ Ax,
                                               float* __restrict__ En) {
  const int lane = threadIdx.x & 31;
  const int i = blockIdx.x * 8 + (threadIdx.x >> 5);
  const float4* Gv = (const float4*)G;
  float4 axf = make_float4(0.f, 0.f, 0.f, 0.f);
  float asq = 0.f;
  int o = off_s[i];
  const int oe = off_s[i + 1];
  for (; o + 4 <= oe; o += 4) {
    int d0 = idx_s[o], d1 = idx_s[o + 1], d2 = idx_s[o + 2], d3 = idx_s[o + 3];
    float4 r0 = Gv[d0 * 32 + lane], r1 = Gv[d1 * 32 + lane];
    float4 r2 = Gv[d2 * 32 + lane], r3 = Gv[d3 * 32 + lane];
    asq += (sq[d0] + sq[d1]) + (sq[d2] + sq[d3]);
    axf = f4_add(axf, f4_add(f4_add(r0, r1), f4_add(r2, r3)));
  }
  for (; o < oe; ++o) {
    int d = idx_s[o];
    axf = f4_add(axf, Gv[d * 32 + lane]);
    asq += sq[d];
  }
  ((float4*)Ax)[i * 32 + lane] = axf;
  float4 gi = Gv[i * 32 + lane];
  float dot = grp_sum32(gi.x * axf.x + gi.y * axf.y + gi.z * axf.z + gi.w * axf.w);
  if (lane == 0) En[i] = 0.5f * (dego[i] * sq[i] + asq - 2.f * dot);
}

// ---------------- softmax over entropies -> c ----------------
__device__ __forceinline__ float red1024(float v, bool domax, float* sm) {
  #pragma unroll
  for (int o = 32; o > 0; o >>= 1) {
    float u = __shfl_down(v, o, 64);
    v = domax ? fmaxf(v, u) : v + u;
  }
  if ((threadIdx.x & 63) == 0) sm[threadIdx.x >> 6] = v;
  __syncthreads();
  if (threadIdx.x == 0) {
    float r = sm[0];
    for (int k = 1; k < 16; ++k) r = domax ? fmaxf(r, sm[k]) : r + sm[k];
    sm[0] = r;
  }
  __syncthreads();
  float r = sm[0];
  __syncthreads();
  return r;
}

__global__ __launch_bounds__(1024) void k_softc(const float* __restrict__ En,
                                                float* __restrict__ c, int n) {
  __shared__ float sm[16];
  const int t = threadIdx.x;
  float m = -1e30f;
  for (int i = t; i < n; i += 1024) m = fmaxf(m, En[i]);
  m = red1024(m, true, sm);
  const float denom = (m + 1e-12f) * TEMP_;
  float se = 0.f;
  for (int i = t; i < n; i += 1024) se += expf(-En[i] / denom);
  se = red1024(se, false, sm);
  const float logZ = logf(se);
  float Sacc = 0.f;
  for (int i = t; i < n; i += 1024) {
    float li = -En[i] / denom;
    float P = expf(li) / se;
    Sacc -= P * (li - logZ);
  }
  float S = red1024(Sacc, false, sm);
  for (int i = t; i < n; i += 1024) {
    float li = -En[i] / denom;
    float P = expf(li) / se;
    c[i] = P * ((li - logZ) + S) / TEMP_;
  }
}

// ---------------- A^T c, A^T(c*g), eg, relu, layernorm ----------------
__global__ __launch_bounds__(256) void k_combine_ln(const float* __restrict__ G,
                                                    const float* __restrict__ Ax,
                                                    const float* __restrict__ cvec,
                                                    const float* __restrict__ dego,
                                                    const int* __restrict__ off_d,
                                                    const int* __restrict__ idx_d,
                                                    const float* __restrict__ gamma,
                                                    const float* __restrict__ beta,
                                                    float* __restrict__ Xout) {
  const int lane = threadIdx.x & 31;
  const int i = blockIdx.x * 8 + (threadIdx.x >> 5);
  const float4* Gv = (const float4*)G;
  const float4 gi = Gv[i * 32 + lane];
  float4 tf = make_float4(0.f, 0.f, 0.f, 0.f);
  float atc = 0.f;
  int o = off_d[i];
  const int oe = off_d[i + 1];
  for (; o + 4 <= oe; o += 4) {
    int s0 = idx_d[o], s1 = idx_d[o + 1], s2 = idx_d[o + 2], s3 = idx_d[o + 3];
    float4 r0 = Gv[s0 * 32 + lane], r1 = Gv[s1 * 32 + lane];
    float4 r2 = Gv[s2 * 32 + lane], r3 = Gv[s3 * 32 + lane];
    float c0 = cvec[s0], c1 = cvec[s1], c2 = cvec[s2], c3 = cvec[s3];
    atc += (c0 + c1) + (c2 + c3);
    tf = f4_fma(c0, r0, tf); tf = f4_fma(c1, r1, tf);
    tf = f4_fma(c2, r2, tf); tf = f4_fma(c3, r3, tf);
  }
  for (; o < oe; ++o) {
    int s = idx_d[o];
    float cs = cvec[s];
    atc += cs;
    tf = f4_fma(cs, Gv[s * 32 + lane], tf);
  }
  const float ci = cvec[i], dg = dego[i];
  const float4 axi = ((const float4*)Ax)[i * 32 + lane];
  float4 v;
  v.x = fmaxf(gi.x + ci * (dg * gi.x - axi.x) + atc * gi.x - tf.x, 0.f);
  v.y = fmaxf(gi.y + ci * (dg * gi.y - axi.y) + atc * gi.y - tf.y, 0.f);
  v.z = fmaxf(gi.z + ci * (dg * gi.z - axi.z) + atc * gi.z - tf.z, 0.f);
  v.w = fmaxf(gi.w + ci * (dg * gi.w - axi.w) + atc * gi.w - tf.w, 0.f);
  float mu = grp_sum32(f4_hsum(v)) * (1.f / 128.f);
  float4 dv;
  dv.x = v.x - mu; dv.y = v.y - mu; dv.z = v.z - mu; dv.w = v.w - mu;
  float var = grp_sum32(dv.x * dv.x + dv.y * dv.y + dv.z * dv.z + dv.w * dv.w) * (1.f / 128.f);
  float rs = rsqrtf(var + LN_EPS_);
  float4 ga = ((const float4*)gamma)[lane];
  float4 be = ((const float4*)beta)[lane];
  float4 out;
  out.x = fmaf(dv.x * rs, ga.x, be.x);
  out.y = fmaf(dv.y * rs, ga.y, be.y);
  out.z = fmaf(dv.z * rs, ga.z, be.z);
  out.w = fmaf(dv.w * rs, ga.w, be.w);
  ((float4*)Xout)[i * 32 + lane] = out;
}

// ---------------- final conv aggregate (DOUT=64): 16 lanes/node ------------
__global__ __launch_bounds__(256) void k_final_agg(const float* __restrict__ H,
                                                   const float* __restrict__ dinv,
                                                   const float* __restrict__ bout,
                                                   const int* __restrict__ off_d,
                                                   const int* __restrict__ idx_d,
                                                   float* __restrict__ out) {
  const int lane = threadIdx.x & 15;
  const int i = blockIdx.x * 16 + (threadIdx.x >> 4);
  const float4* Hv = (const float4*)H;
  const float di = dinv[i];
  float4 acc = Hv[i * 16 + lane];
  acc.x *= di; acc.y *= di; acc.z *= di; acc.w *= di;
  int o = off_d[i];
  const int oe = off_d[i + 1];
  for (; o + 4 <= oe; o += 4) {
    int s0 = idx_d[o], s1 = idx_d[o + 1], s2 = idx_d[o + 2], s3 = idx_d[o + 3];
    float4 r0 = Hv[s0 * 16 + lane], r1 = Hv[s1 * 16 + lane];
    float4 r2 = Hv[s2 * 16 + lane], r3 = Hv[s3 * 16 + lane];
    acc = f4_fma(dinv[s0], r0, acc); acc = f4_fma(dinv[s1], r1, acc);
    acc = f4_fma(dinv[s2], r2, acc); acc = f4_fma(dinv[s3], r3, acc);
  }
  for (; o < oe; ++o) {
    int s = idx_d[o];
    acc = f4_fma(dinv[s], Hv[s * 16 + lane], acc);
  }
  float4 bb = ((const float4*)bout)[lane];
  float4 r;
  r.x = fmaf(di, acc.x, bb.x); r.y = fmaf(di, acc.y, bb.y);
  r.z = fmaf(di, acc.z, bb.z); r.w = fmaf(di, acc.w, bb.w);
  ((float4*)out)[i * 16 + lane] = r;
}

extern "C" void kernel_launch(void* const* d_in, const int* in_sizes, int n_in,
                              void* d_out, int out_size, void* d_ws, size_t ws_size,
                              hipStream_t stream) {
  const float* x    = (const float*)d_in[0];
  const int*   ei   = (const int*)d_in[1];
  const float* W1   = (const float*)d_in[2];
  const float* b1   = (const float*)d_in[3];
  const float* W2   = (const float*)d_in[4];
  const float* b2   = (const float*)d_in[5];
  const float* Wout = (const float*)d_in[6];
  const float* bout = (const float*)d_in[7];
  const float* gam  = (const float*)d_in[8];
  const float* bet  = (const float*)d_in[9];
  float* out = (float*)d_out;

  const int N = in_sizes[0] / DH;   // 8000
  const int E = in_sizes[1] / 2;    // 256000

  float* ws = (float*)d_ws;
  float* xf = ws;   ws += N * DH;
  float* h0 = ws;   ws += N * DH;
  float* G  = ws;   ws += N * DH;
  float* Ax = ws;   ws += N * DH;
  float* sq = ws;   ws += N;
  float* En = ws;   ws += N;
  float* cv = ws;   ws += N;
  float* dinv = ws; ws += N;
  float* dego = ws; ws += N;
  int* cnt_d = (int*)ws; ws += N;
  int* cnt_s = (int*)ws; ws += N;
  int* off_d = (int*)ws; ws += N + 4;
  int* off_s = (int*)ws; ws += N + 4;
  int* idx_d = (int*)ws; ws += E;
  int* idx_s = (int*)ws; ws += E;

  hipMemsetAsync(cnt_d, 0, N * sizeof(int), stream);
  hipMemsetAsync(cnt_s, 0, N * sizeof(int), stream);
  k_hist<<<(E + 255) / 256, 256, 0, stream>>>(ei, E, cnt_d, cnt_s);
  k_scan<<<1, 1024, 0, stream>>>(cnt_d, cnt_s, off_d, off_s, dinv, dego, N);
  k_fill<<<(E + 255) / 256, 256, 0, stream>>>(ei, E, off_d, off_s, cnt_d, cnt_s,
                                              idx_d, idx_s);

  const float* xin = x;
  const float* Wl[2] = {W1, W2};
  const float* bl[2] = {b1, b2};
  for (int l = 0; l < 2; ++l) {
    k_gemm<DH><<<N / 16, 256, 0, stream>>>(xin, Wl[l], h0);
    k_conv_agg<<<N / 8, 256, 0, stream>>>(h0, dinv, bl[l], off_d, idx_d, G, sq);
    k_ax_en<<<N / 8, 256, 0, stream>>>(G, sq, dego, off_s, idx_s, Ax, En);
    k_softc<<<1, 1024, 0, stream>>>(En, cv, N);
    k_combine_ln<<<N / 8, 256, 0, stream>>>(G, Ax, cv, dego, off_d, idx_d, gam, bet, xf);
    xin = xf;
  }
  k_gemm<64><<<N / 16, 256, 0, stream>>>(xf, Wout, h0);
  k_final_agg<<<N / 16, 256, 0, stream>>>(h0, dinv, bout, off_d, idx_d, out);
}

// Round 4
// 277.275 us; speedup vs baseline: 1.3991x; 1.0813x over previous
//
#include <hip/hip_runtime.h>
#include <hip/hip_bf16.h>

#define DH 128

static constexpr float TEMP_ = 10.0f;
static constexpr float LN_EPS_ = 1e-5f;

// ---------------- bf16 helpers ----------------
__device__ __forceinline__ float bf2f(unsigned short u) {
  union { unsigned int i; float f; } v; v.i = ((unsigned int)u) << 16; return v.f;
}
__device__ __forceinline__ unsigned short f2bf(float f) {
  union { float f; unsigned int i; } v; v.f = f;
  unsigned int b = v.i + 0x7FFFu + ((v.i >> 16) & 1u);   // RNE
  return (unsigned short)(b >> 16);
}
__device__ __forceinline__ float4 us4f4(ushort4 u) {
  return make_float4(bf2f(u.x), bf2f(u.y), bf2f(u.z), bf2f(u.w));
}
__device__ __forceinline__ ushort4 f4us4(float4 f) {
  ushort4 u; u.x = f2bf(f.x); u.y = f2bf(f.y); u.z = f2bf(f.z); u.w = f2bf(f.w);
  return u;
}

// ---------------- float4 helpers ----------------
__device__ __forceinline__ float4 f4_fma(float a, float4 x, float4 y) {
  y.x = fmaf(a, x.x, y.x); y.y = fmaf(a, x.y, y.y);
  y.z = fmaf(a, x.z, y.z); y.w = fmaf(a, x.w, y.w);
  return y;
}
__device__ __forceinline__ float4 f4_add(float4 a, float4 b) {
  a.x += b.x; a.y += b.y; a.z += b.z; a.w += b.w; return a;
}
__device__ __forceinline__ float f4_hsum(float4 a) { return (a.x + a.y) + (a.z + a.w); }

__device__ __forceinline__ float grp_sum32(float v) {
  #pragma unroll
  for (int o = 16; o > 0; o >>= 1) v += __shfl_down(v, o, 32);
  return __shfl(v, 0, 32);
}

// ---------------- CSR build ----------------
__global__ void k_hist(const int* __restrict__ ei, int E, int* cnt_d, int* cnt_s) {
  int e = blockIdx.x * blockDim.x + threadIdx.x;
  if (e < E) {
    atomicAdd(&cnt_s[ei[e]], 1);       // src = ei[0][e]
    atomicAdd(&cnt_d[ei[E + e]], 1);   // dst = ei[1][e]
  }
}

// grid = 2: block 0 scans cnt_d -> off_d/dinv, block 1 scans cnt_s -> off_s/dego
__global__ __launch_bounds__(1024) void k_scan(int* cnt_d, int* cnt_s,
                                               int* off_d, int* off_s,
                                               float* dinv, float* dego, int n) {
  __shared__ int sm[1024];
  const int t = threadIdx.x;
  const int pass = blockIdx.x;
  int* cnt = pass ? cnt_s : cnt_d;
  int* off = pass ? off_s : off_d;
  const int base = t * 8;
  int lc[8]; int s = 0;
  #pragma unroll
  for (int j = 0; j < 8; ++j) {
    int idx = base + j;
    int v = (idx < n) ? cnt[idx] : 0;
    lc[j] = v; s += v;
  }
  sm[t] = s; __syncthreads();
  for (int o = 1; o < 1024; o <<= 1) {
    int v = (t >= o) ? sm[t - o] : 0;
    __syncthreads();
    sm[t] += v;
    __syncthreads();
  }
  int run = sm[t] - s;
  int total = sm[1023];
  #pragma unroll
  for (int j = 0; j < 8; ++j) {
    int idx = base + j;
    if (idx < n) {
      off[idx] = run; run += lc[j];
      if (pass == 0) dinv[idx] = rsqrtf((float)lc[j] + 1.0f);
      else           dego[idx] = (float)lc[j];
      cnt[idx] = 0;
    }
  }
  if (t == 0) off[n] = total;
}

__global__ void k_fill(const int* __restrict__ ei, int E,
                       const int* __restrict__ off_d, const int* __restrict__ off_s,
                       int* cnt_d, int* cnt_s, int* idx_d, int* idx_s) {
  int e = blockIdx.x * blockDim.x + threadIdx.x;
  if (e < E) {
    int s = ei[e], d = ei[E + e];
    int p = atomicAdd(&cnt_d[d], 1);
    idx_d[off_d[d] + p] = s;
    int q = atomicAdd(&cnt_s[s], 1);
    idx_s[off_s[s] + q] = d;
  }
}

// ------- GEMM: Hb[n,DOUT](bf16) = X[n,128](fp32) @ W[128,DOUT] -------------
template <int DOUT>
__global__ __launch_bounds__(256) void k_gemm(const float* __restrict__ X,
                                              const float* __restrict__ W,
                                              unsigned short* __restrict__ Hb) {
  __shared__ float Ws[64 * DOUT];
  __shared__ float xs[16 * 128];
  const int t = threadIdx.x;
  const int row0 = blockIdx.x * 16;

  const float4* xg = (const float4*)(X + row0 * 128);
  float4* xs4 = (float4*)xs;
  xs4[t] = xg[t];
  xs4[t + 256] = xg[t + 256];

  constexpr int RPT = (16 * DOUT) / 256;
  const int c = t % DOUT;
  const int rg = t / DOUT;
  float acc[RPT];
  #pragma unroll
  for (int r = 0; r < RPT; ++r) acc[r] = 0.f;

  for (int kt = 0; kt < 2; ++kt) {
    __syncthreads();
    for (int i = t; i < 64 * DOUT; i += 256) Ws[i] = W[kt * 64 * DOUT + i];
    __syncthreads();
    for (int k = 0; k < 64; ++k) {
      float wv = Ws[k * DOUT + c];
      #pragma unroll
      for (int r = 0; r < RPT; ++r)
        acc[r] += xs[(rg * RPT + r) * 128 + kt * 64 + k] * wv;
    }
  }
  #pragma unroll
  for (int r = 0; r < RPT; ++r)
    Hb[(row0 + rg * RPT + r) * DOUT + c] = f2bf(acc[r]);
}

// ------- conv aggregate: 32 lanes/node, ushort4(bf16 x4)/lane --------------
__global__ __launch_bounds__(256) void k_conv_agg(const unsigned short* __restrict__ Hb,
                                                  const float* __restrict__ dinv,
                                                  const float* __restrict__ b,
                                                  const int* __restrict__ off_d,
                                                  const int* __restrict__ idx_d,
                                                  float* __restrict__ G,
                                                  unsigned short* __restrict__ Gb,
                                                  float* __restrict__ sq) {
  const int lane = threadIdx.x & 31;
  const int i = blockIdx.x * 8 + (threadIdx.x >> 5);
  const ushort4* Hv = (const ushort4*)Hb;
  const float di = dinv[i];
  float4 acc = us4f4(Hv[i * 32 + lane]);
  acc.x *= di; acc.y *= di; acc.z *= di; acc.w *= di;   // self loop
  int o = off_d[i];
  const int oe = off_d[i + 1];
  for (; o + 4 <= oe; o += 4) {
    int s0 = idx_d[o], s1 = idx_d[o + 1], s2 = idx_d[o + 2], s3 = idx_d[o + 3];
    ushort4 r0 = Hv[s0 * 32 + lane], r1 = Hv[s1 * 32 + lane];
    ushort4 r2 = Hv[s2 * 32 + lane], r3 = Hv[s3 * 32 + lane];
    float d0 = dinv[s0], d1 = dinv[s1], d2 = dinv[s2], d3 = dinv[s3];
    acc = f4_fma(d0, us4f4(r0), acc); acc = f4_fma(d1, us4f4(r1), acc);
    acc = f4_fma(d2, us4f4(r2), acc); acc = f4_fma(d3, us4f4(r3), acc);
  }
  for (; o < oe; ++o) {
    int s = idx_d[o];
    acc = f4_fma(dinv[s], us4f4(Hv[s * 32 + lane]), acc);
  }
  float4 bb = ((const float4*)b)[lane];
  float4 gi;
  gi.x = fmaf(di, acc.x, bb.x); gi.y = fmaf(di, acc.y, bb.y);
  gi.z = fmaf(di, acc.z, bb.z); gi.w = fmaf(di, acc.w, bb.w);
  ((float4*)G)[i * 32 + lane] = gi;
  ((ushort4*)Gb)[i * 32 + lane] = f4us4(gi);
  float s2 = grp_sum32(gi.x * gi.x + gi.y * gi.y + gi.z * gi.z + gi.w * gi.w);
  if (lane == 0) sq[i] = s2;
}

// ------- Ax = A@G (CSR_src), Asq, En -------------------------------------
__global__ __launch_bounds__(256) void k_ax_en(const float* __restrict__ G,
                                               const unsigned short* __restrict__ Gb,
                                               const float* __restrict__ sq,
                                               const float* __restrict__ dego,
                                               const int* __restrict__ off_s,
                                               const int* __restrict__ idx_s,
                                               float* __restrict__ Ax,
                                               float* __restrict__ En) {
  const int lane = threadIdx.x & 31;
  const int i = blockIdx.x * 8 + (threadIdx.x >> 5);
  const ushort4* Gv = (const ushort4*)Gb;
  float4 axf = make_float4(0.f, 0.f, 0.f, 0.f);
  float asq = 0.f;
  int o = off_s[i];
  const int oe = off_s[i + 1];
  for (; o + 4 <= oe; o += 4) {
    int d0 = idx_s[o], d1 = idx_s[o + 1], d2 = idx_s[o + 2], d3 = idx_s[o + 3];
    ushort4 r0 = Gv[d0 * 32 + lane], r1 = Gv[d1 * 32 + lane];
    ushort4 r2 = Gv[d2 * 32 + lane], r3 = Gv[d3 * 32 + lane];
    asq += (sq[d0] + sq[d1]) + (sq[d2] + sq[d3]);
    axf = f4_add(axf, f4_add(f4_add(us4f4(r0), us4f4(r1)),
                             f4_add(us4f4(r2), us4f4(r3))));
  }
  for (; o < oe; ++o) {
    int d = idx_s[o];
    axf = f4_add(axf, us4f4(Gv[d * 32 + lane]));
    asq += sq[d];
  }
  ((float4*)Ax)[i * 32 + lane] = axf;
  float4 gi = ((const float4*)G)[i * 32 + lane];
  float dot = grp_sum32(gi.x * axf.x + gi.y * axf.y + gi.z * axf.z + gi.w * axf.w);
  if (lane == 0) En[i] = 0.5f * (dego[i] * sq[i] + asq - 2.f * dot);
}

// ---------------- softmax over entropies -> c (single block) ---------------
__device__ __forceinline__ float red1024(float v, bool domax, float* sm) {
  #pragma unroll
  for (int o = 32; o > 0; o >>= 1) {
    float u = __shfl_down(v, o, 64);
    v = domax ? fmaxf(v, u) : v + u;
  }
  if ((threadIdx.x & 63) == 0) sm[threadIdx.x >> 6] = v;
  __syncthreads();
  if (threadIdx.x == 0) {
    float r = sm[0];
    for (int k = 1; k < 16; ++k) r = domax ? fmaxf(r, sm[k]) : r + sm[k];
    sm[0] = r;
  }
  __syncthreads();
  float r = sm[0];
  __syncthreads();
  return r;
}

__global__ __launch_bounds__(1024) void k_softc(const float* __restrict__ En,
                                                float* __restrict__ c, int n) {
  __shared__ float sm[16];
  const int t = threadIdx.x;
  float m = -1e30f;
  for (int i = t; i < n; i += 1024) m = fmaxf(m, En[i]);
  m = red1024(m, true, sm);
  const float denom = (m + 1e-12f) * TEMP_;
  float se = 0.f;
  for (int i = t; i < n; i += 1024) se += expf(-En[i] / denom);
  se = red1024(se, false, sm);
  const float logZ = logf(se);
  float Sacc = 0.f;
  for (int i = t; i < n; i += 1024) {
    float li = -En[i] / denom;
    float P = expf(li) / se;
    Sacc -= P * (li - logZ);
  }
  float S = red1024(Sacc, false, sm);
  for (int i = t; i < n; i += 1024) {
    float li = -En[i] / denom;
    float P = expf(li) / se;
    c[i] = P * ((li - logZ) + S) / TEMP_;
  }
}

// ------- A^T c, A^T(c*g), eg, relu, layernorm ------------------------------
__global__ __launch_bounds__(256) void k_combine_ln(const float* __restrict__ G,
                                                    const unsigned short* __restrict__ Gb,
                                                    const float* __restrict__ Ax,
                                                    const float* __restrict__ cvec,
                                                    const float* __restrict__ dego,
                                                    const int* __restrict__ off_d,
                                                    const int* __restrict__ idx_d,
                                                    const float* __restrict__ gamma,
                                                    const float* __restrict__ beta,
                                                    float* __restrict__ Xout) {
  const int lane = threadIdx.x & 31;
  const int i = blockIdx.x * 8 + (threadIdx.x >> 5);
  const ushort4* Gv = (const ushort4*)Gb;
  const float4 gi = ((const float4*)G)[i * 32 + lane];
  float4 tf = make_float4(0.f, 0.f, 0.f, 0.f);
  float atc = 0.f;
  int o = off_d[i];
  const int oe = off_d[i + 1];
  for (; o + 4 <= oe; o += 4) {
    int s0 = idx_d[o], s1 = idx_d[o + 1], s2 = idx_d[o + 2], s3 = idx_d[o + 3];
    ushort4 r0 = Gv[s0 * 32 + lane], r1 = Gv[s1 * 32 + lane];
    ushort4 r2 = Gv[s2 * 32 + lane], r3 = Gv[s3 * 32 + lane];
    float c0 = cvec[s0], c1 = cvec[s1], c2 = cvec[s2], c3 = cvec[s3];
    atc += (c0 + c1) + (c2 + c3);
    tf = f4_fma(c0, us4f4(r0), tf); tf = f4_fma(c1, us4f4(r1), tf);
    tf = f4_fma(c2, us4f4(r2), tf); tf = f4_fma(c3, us4f4(r3), tf);
  }
  for (; o < oe; ++o) {
    int s = idx_d[o];
    float cs = cvec[s];
    atc += cs;
    tf = f4_fma(cs, us4f4(Gv[s * 32 + lane]), tf);
  }
  const float ci = cvec[i], dg = dego[i];
  const float4 axi = ((const float4*)Ax)[i * 32 + lane];
  float4 v;
  v.x = fmaxf(gi.x + ci * (dg * gi.x - axi.x) + atc * gi.x - tf.x, 0.f);
  v.y = fmaxf(gi.y + ci * (dg * gi.y - axi.y) + atc * gi.y - tf.y, 0.f);
  v.z = fmaxf(gi.z + ci * (dg * gi.z - axi.z) + atc * gi.z - tf.z, 0.f);
  v.w = fmaxf(gi.w + ci * (dg * gi.w - axi.w) + atc * gi.w - tf.w, 0.f);
  float mu = grp_sum32(f4_hsum(v)) * (1.f / 128.f);
  float4 dv;
  dv.x = v.x - mu; dv.y = v.y - mu; dv.z = v.z - mu; dv.w = v.w - mu;
  float var = grp_sum32(dv.x * dv.x + dv.y * dv.y + dv.z * dv.z + dv.w * dv.w) * (1.f / 128.f);
  float rs = rsqrtf(var + LN_EPS_);
  float4 ga = ((const float4*)gamma)[lane];
  float4 be = ((const float4*)beta)[lane];
  float4 out;
  out.x = fmaf(dv.x * rs, ga.x, be.x);
  out.y = fmaf(dv.y * rs, ga.y, be.y);
  out.z = fmaf(dv.z * rs, ga.z, be.z);
  out.w = fmaf(dv.w * rs, ga.w, be.w);
  ((float4*)Xout)[i * 32 + lane] = out;
}

// ------- final conv aggregate (DOUT=64, bf16 rows): 16 lanes/node ----------
__global__ __launch_bounds__(256) void k_final_agg(const unsigned short* __restrict__ Hb,
                                                   const float* __restrict__ dinv,
                                                   const float* __restrict__ bout,
                                                   const int* __restrict__ off_d,
                                                   const int* __restrict__ idx_d,
                                                   float* __restrict__ out) {
  const int lane = threadIdx.x & 15;
  const int i = blockIdx.x * 16 + (threadIdx.x >> 4);
  const ushort4* Hv = (const ushort4*)Hb;
  const float di = dinv[i];
  float4 acc = us4f4(Hv[i * 16 + lane]);
  acc.x *= di; acc.y *= di; acc.z *= di; acc.w *= di;
  int o = off_d[i];
  const int oe = off_d[i + 1];
  for (; o + 4 <= oe; o += 4) {
    int s0 = idx_d[o], s1 = idx_d[o + 1], s2 = idx_d[o + 2], s3 = idx_d[o + 3];
    ushort4 r0 = Hv[s0 * 16 + lane], r1 = Hv[s1 * 16 + lane];
    ushort4 r2 = Hv[s2 * 16 + lane], r3 = Hv[s3 * 16 + lane];
    acc = f4_fma(dinv[s0], us4f4(r0), acc); acc = f4_fma(dinv[s1], us4f4(r1), acc);
    acc = f4_fma(dinv[s2], us4f4(r2), acc); acc = f4_fma(dinv[s3], us4f4(r3), acc);
  }
  for (; o < oe; ++o) {
    int s = idx_d[o];
    acc = f4_fma(dinv[s], us4f4(Hv[s * 16 + lane]), acc);
  }
  float4 bb = ((const float4*)bout)[lane];
  float4 r;
  r.x = fmaf(di, acc.x, bb.x); r.y = fmaf(di, acc.y, bb.y);
  r.z = fmaf(di, acc.z, bb.z); r.w = fmaf(di, acc.w, bb.w);
  ((float4*)out)[i * 16 + lane] = r;
}

extern "C" void kernel_launch(void* const* d_in, const int* in_sizes, int n_in,
                              void* d_out, int out_size, void* d_ws, size_t ws_size,
                              hipStream_t stream) {
  const float* x    = (const float*)d_in[0];
  const int*   ei   = (const int*)d_in[1];
  const float* W1   = (const float*)d_in[2];
  const float* b1   = (const float*)d_in[3];
  const float* W2   = (const float*)d_in[4];
  const float* b2   = (const float*)d_in[5];
  const float* Wout = (const float*)d_in[6];
  const float* bout = (const float*)d_in[7];
  const float* gam  = (const float*)d_in[8];
  const float* bet  = (const float*)d_in[9];
  float* out = (float*)d_out;

  const int N = in_sizes[0] / DH;   // 8000
  const int E = in_sizes[1] / 2;    // 256000

  float* ws = (float*)d_ws;
  float* xf = ws;   ws += N * DH;
  float* G  = ws;   ws += N * DH;
  float* Ax = ws;   ws += N * DH;
  float* sq = ws;   ws += N;
  float* En = ws;   ws += N;
  float* cv = ws;   ws += N;
  float* dinv = ws; ws += N;
  float* dego = ws; ws += N;
  unsigned short* Hb = (unsigned short*)ws; ws += N * DH / 2;   // bf16 N x 128
  unsigned short* Gb = (unsigned short*)ws; ws += N * DH / 2;   // bf16 N x 128
  int* cnt_d = (int*)ws; ws += N;
  int* cnt_s = (int*)ws; ws += N;
  int* off_d = (int*)ws; ws += N + 4;
  int* off_s = (int*)ws; ws += N + 4;
  int* idx_d = (int*)ws; ws += E;
  int* idx_s = (int*)ws; ws += E;

  hipMemsetAsync(cnt_d, 0, 2 * N * sizeof(int), stream);  // cnt_d, cnt_s
  k_hist<<<(E + 255) / 256, 256, 0, stream>>>(ei, E, cnt_d, cnt_s);
  k_scan<<<2, 1024, 0, stream>>>(cnt_d, cnt_s, off_d, off_s, dinv, dego, N);
  k_fill<<<(E + 255) / 256, 256, 0, stream>>>(ei, E, off_d, off_s, cnt_d, cnt_s,
                                              idx_d, idx_s);

  const float* xin = x;
  const float* Wl[2] = {W1, W2};
  const float* bl[2] = {b1, b2};
  for (int l = 0; l < 2; ++l) {
    k_gemm<DH><<<N / 16, 256, 0, stream>>>(xin, Wl[l], Hb);
    k_conv_agg<<<N / 8, 256, 0, stream>>>(Hb, dinv, bl[l], off_d, idx_d, G, Gb, sq);
    k_ax_en<<<N / 8, 256, 0, stream>>>(G, Gb, sq, dego, off_s, idx_s, Ax, En);
    k_softc<<<1, 1024, 0, stream>>>(En, cv, N);
    k_combine_ln<<<N / 8, 256, 0, stream>>>(G, Gb, Ax, cv, dego, off_d, idx_d,
                                            gam, bet, xf);
    xin = xf;
  }
  k_gemm<64><<<N / 16, 256, 0, stream>>>(xf, Wout, Hb);
  k_final_agg<<<N / 16, 256, 0, stream>>>(Hb, dinv, bout, off_d, idx_d, out);
}

// Round 7
// 271.159 us; speedup vs baseline: 1.4307x; 1.0226x over previous
//
#include <hip/hip_runtime.h>
#include <hip/hip_bf16.h>

#define DH 128

static constexpr float TEMP_ = 10.0f;
static constexpr float LN_EPS_ = 1e-5f;

// ---------------- bf16 helpers ----------------
__device__ __forceinline__ float bf2f(unsigned short u) {
  union { unsigned int i; float f; } v; v.i = ((unsigned int)u) << 16; return v.f;
}
__device__ __forceinline__ unsigned short f2bf(float f) {
  union { float f; unsigned int i; } v; v.f = f;
  unsigned int b = v.i + 0x7FFFu + ((v.i >> 16) & 1u);   // RNE
  return (unsigned short)(b >> 16);
}
__device__ __forceinline__ float4 us4f4(ushort4 u) {
  return make_float4(bf2f(u.x), bf2f(u.y), bf2f(u.z), bf2f(u.w));
}
__device__ __forceinline__ ushort4 f4us4(float4 f) {
  ushort4 u; u.x = f2bf(f.x); u.y = f2bf(f.y); u.z = f2bf(f.z); u.w = f2bf(f.w);
  return u;
}

// ---------------- float4 helpers ----------------
__device__ __forceinline__ float4 f4_fma(float a, float4 x, float4 y) {
  y.x = fmaf(a, x.x, y.x); y.y = fmaf(a, x.y, y.y);
  y.z = fmaf(a, x.z, y.z); y.w = fmaf(a, x.w, y.w);
  return y;
}
__device__ __forceinline__ float4 f4_add(float4 a, float4 b) {
  a.x += b.x; a.y += b.y; a.z += b.z; a.w += b.w; return a;
}
__device__ __forceinline__ float f4_hsum(float4 a) { return (a.x + a.y) + (a.z + a.w); }

__device__ __forceinline__ float grp_sum32(float v) {
  #pragma unroll
  for (int o = 16; o > 0; o >>= 1) v += __shfl_down(v, o, 32);
  return __shfl(v, 0, 32);
}

// 256-thread block reduce; s4 = 4-float LDS scratch. Returns to all threads.
__device__ __forceinline__ float blkred(float v, bool mx, float* s4) {
  const int t = threadIdx.x;
  #pragma unroll
  for (int o = 32; o > 0; o >>= 1) {
    float u = __shfl_down(v, o, 64);
    v = mx ? fmaxf(v, u) : v + u;
  }
  __syncthreads();
  if ((t & 63) == 0) s4[t >> 6] = v;
  __syncthreads();
  float r = mx ? fmaxf(fmaxf(s4[0], s4[1]), fmaxf(s4[2], s4[3]))
               : (s4[0] + s4[1]) + (s4[2] + s4[3]);
  __syncthreads();
  return r;
}

// ---------- fused: layer-1 GEMM (blocks < NT) + degree histogram ----------
__global__ __launch_bounds__(256) void k_gemm1_hist(const float* __restrict__ X,
                                                    const float* __restrict__ W,
                                                    unsigned short* __restrict__ Hb,
                                                    const int* __restrict__ ei, int E,
                                                    int* cnt_d, int* cnt_s, int NT) {
  __shared__ float Ws[64 * DH];
  __shared__ float xs[16 * 128];
  const int t = threadIdx.x;
  if ((int)blockIdx.x < NT) {
    const int row0 = blockIdx.x * 16;
    const float4* xg = (const float4*)(X + row0 * 128);
    float4* xs4 = (float4*)xs;
    xs4[t] = xg[t];
    xs4[t + 256] = xg[t + 256];
    const int c = t & 127, rg = t >> 7;   // RPT = 8
    float acc[8];
    #pragma unroll
    for (int r = 0; r < 8; ++r) acc[r] = 0.f;
    for (int kt = 0; kt < 2; ++kt) {
      __syncthreads();
      for (int i = t; i < 64 * DH; i += 256) Ws[i] = W[kt * 64 * DH + i];
      __syncthreads();
      for (int k = 0; k < 64; ++k) {
        float wv = Ws[k * DH + c];
        #pragma unroll
        for (int r = 0; r < 8; ++r)
          acc[r] += xs[(rg * 8 + r) * 128 + kt * 64 + k] * wv;
      }
    }
    #pragma unroll
    for (int r = 0; r < 8; ++r)
      Hb[(row0 + rg * 8 + r) * DH + c] = f2bf(acc[r]);
  } else {
    const int nb = gridDim.x - NT;
    for (int e = (blockIdx.x - NT) * 256 + t; e < E; e += nb * 256) {
      atomicAdd(&cnt_s[ei[e]], 1);
      atomicAdd(&cnt_d[ei[E + e]], 1);
    }
  }
}

// ------- GEMM: Hb[n,DOUT](bf16) = X[n,128](fp32) @ W[128,DOUT] -------------
template <int DOUT>
__global__ __launch_bounds__(256) void k_gemm(const float* __restrict__ X,
                                              const float* __restrict__ W,
                                              unsigned short* __restrict__ Hb) {
  __shared__ float Ws[64 * DOUT];
  __shared__ float xs[16 * 128];
  const int t = threadIdx.x;
  const int row0 = blockIdx.x * 16;

  const float4* xg = (const float4*)(X + row0 * 128);
  float4* xs4 = (float4*)xs;
  xs4[t] = xg[t];
  xs4[t + 256] = xg[t + 256];

  constexpr int RPT = (16 * DOUT) / 256;
  const int c = t % DOUT;
  const int rg = t / DOUT;
  float acc[RPT];
  #pragma unroll
  for (int r = 0; r < RPT; ++r) acc[r] = 0.f;

  for (int kt = 0; kt < 2; ++kt) {
    __syncthreads();
    for (int i = t; i < 64 * DOUT; i += 256) Ws[i] = W[kt * 64 * DOUT + i];
    __syncthreads();
    for (int k = 0; k < 64; ++k) {
      float wv = Ws[k * DOUT + c];
      #pragma unroll
      for (int r = 0; r < RPT; ++r)
        acc[r] += xs[(rg * RPT + r) * 128 + kt * 64 + k] * wv;
    }
  }
  #pragma unroll
  for (int r = 0; r < RPT; ++r)
    Hb[(row0 + rg * RPT + r) * DOUT + c] = f2bf(acc[r]);
}

// grid = 2: block 0 scans cnt_d -> off_d/dinv, block 1 scans cnt_s -> off_s/dego
__global__ __launch_bounds__(1024) void k_scan(int* cnt_d, int* cnt_s,
                                               int* off_d, int* off_s,
                                               float* dinv, float* dego, int n) {
  __shared__ int sm[1024];
  const int t = threadIdx.x;
  const int pass = blockIdx.x;
  int* cnt = pass ? cnt_s : cnt_d;
  int* off = pass ? off_s : off_d;
  const int base = t * 8;
  int lc[8]; int s = 0;
  #pragma unroll
  for (int j = 0; j < 8; ++j) {
    int idx = base + j;
    int v = (idx < n) ? cnt[idx] : 0;
    lc[j] = v; s += v;
  }
  sm[t] = s; __syncthreads();
  for (int o = 1; o < 1024; o <<= 1) {
    int v = (t >= o) ? sm[t - o] : 0;
    __syncthreads();
    sm[t] += v;
    __syncthreads();
  }
  int run = sm[t] - s;
  int total = sm[1023];
  #pragma unroll
  for (int j = 0; j < 8; ++j) {
    int idx = base + j;
    if (idx < n) {
      off[idx] = run; run += lc[j];
      if (pass == 0) dinv[idx] = rsqrtf((float)lc[j] + 1.0f);
      else           dego[idx] = (float)lc[j];
      cnt[idx] = 0;
    }
  }
  if (t == 0) off[n] = total;
}

__global__ void k_fill(const int* __restrict__ ei, int E,
                       const int* __restrict__ off_d, const int* __restrict__ off_s,
                       int* cnt_d, int* cnt_s, int* idx_d, int* idx_s) {
  int e = blockIdx.x * blockDim.x + threadIdx.x;
  if (e < E) {
    int s = ei[e], d = ei[E + e];
    int p = atomicAdd(&cnt_d[d], 1);
    idx_d[off_d[d] + p] = s;
    int q = atomicAdd(&cnt_s[s], 1);
    idx_s[off_s[s] + q] = d;
  }
}

// ------- conv aggregate: 32 lanes/node, ushort4(bf16 x4)/lane --------------
__global__ __launch_bounds__(256) void k_conv_agg(const unsigned short* __restrict__ Hb,
                                                  const float* __restrict__ dinv,
                                                  const float* __restrict__ b,
                                                  const int* __restrict__ off_d,
                                                  const int* __restrict__ idx_d,
                                                  float* __restrict__ G,
                                                  unsigned short* __restrict__ Gb,
                                                  float* __restrict__ sq) {
  const int lane = threadIdx.x & 31;
  const int i = blockIdx.x * 8 + (threadIdx.x >> 5);
  const ushort4* Hv = (const ushort4*)Hb;
  const float di = dinv[i];
  float4 acc = us4f4(Hv[i * 32 + lane]);
  acc.x *= di; acc.y *= di; acc.z *= di; acc.w *= di;   // self loop
  int o = off_d[i];
  const int oe = off_d[i + 1];
  for (; o + 4 <= oe; o += 4) {
    int s0 = idx_d[o], s1 = idx_d[o + 1], s2 = idx_d[o + 2], s3 = idx_d[o + 3];
    ushort4 r0 = Hv[s0 * 32 + lane], r1 = Hv[s1 * 32 + lane];
    ushort4 r2 = Hv[s2 * 32 + lane], r3 = Hv[s3 * 32 + lane];
    float d0 = dinv[s0], d1 = dinv[s1], d2 = dinv[s2], d3 = dinv[s3];
    acc = f4_fma(d0, us4f4(r0), acc); acc = f4_fma(d1, us4f4(r1), acc);
    acc = f4_fma(d2, us4f4(r2), acc); acc = f4_fma(d3, us4f4(r3), acc);
  }
  for (; o < oe; ++o) {
    int s = idx_d[o];
    acc = f4_fma(dinv[s], us4f4(Hv[s * 32 + lane]), acc);
  }
  float4 bb = ((const float4*)b)[lane];
  float4 gi;
  gi.x = fmaf(di, acc.x, bb.x); gi.y = fmaf(di, acc.y, bb.y);
  gi.z = fmaf(di, acc.z, bb.z); gi.w = fmaf(di, acc.w, bb.w);
  ((float4*)G)[i * 32 + lane] = gi;
  ((ushort4*)Gb)[i * 32 + lane] = f4us4(gi);
  float s2 = grp_sum32(gi.x * gi.x + gi.y * gi.y + gi.z * gi.z + gi.w * gi.w);
  if (lane == 0) sq[i] = s2;
}

// ------- Ax = A@G (CSR_src), Asq, En -------------------------------------
__global__ __launch_bounds__(256) void k_ax_en(const float* __restrict__ G,
                                               const unsigned short* __restrict__ Gb,
                                               const float* __restrict__ sq,
                                               const float* __restrict__ dego,
                                               const int* __restrict__ off_s,
                                               const int* __restrict__ idx_s,
                                               float* __restrict__ Ax,
                                               float* __restrict__ En) {
  const int lane = threadIdx.x & 31;
  const int i = blockIdx.x * 8 + (threadIdx.x >> 5);
  const ushort4* Gv = (const ushort4*)Gb;
  float4 axf = make_float4(0.f, 0.f, 0.f, 0.f);
  float asq = 0.f;
  int o = off_s[i];
  const int oe = off_s[i + 1];
  for (; o + 4 <= oe; o += 4) {
    int d0 = idx_s[o], d1 = idx_s[o + 1], d2 = idx_s[o + 2], d3 = idx_s[o + 3];
    ushort4 r0 = Gv[d0 * 32 + lane], r1 = Gv[d1 * 32 + lane];
    ushort4 r2 = Gv[d2 * 32 + lane], r3 = Gv[d3 * 32 + lane];
    asq += (sq[d0] + sq[d1]) + (sq[d2] + sq[d3]);
    axf = f4_add(axf, f4_add(f4_add(us4f4(r0), us4f4(r1)),
                             f4_add(us4f4(r2), us4f4(r3))));
  }
  for (; o < oe; ++o) {
    int d = idx_s[o];
    axf = f4_add(axf, us4f4(Gv[d * 32 + lane]));
    asq += sq[d];
  }
  ((float4*)Ax)[i * 32 + lane] = axf;
  float4 gi = ((const float4*)G)[i * 32 + lane];
  float dot = grp_sum32(gi.x * axf.x + gi.y * axf.y + gi.z * axf.z + gi.w * axf.w);
  if (lane == 0) En[i] = 0.5f * (dego[i] * sq[i] + asq - 2.f * dot);
}

// ------- combine: inline softmax stats + A^T c, A^T(c*g), eg, relu, LN -----
// Per-block prologue: reduce En (size n) for max, sum(exp), sum(exp*li); each
// block derives identical (denom, se, logZ, S). Per-edge c_s computed on the
// fly from En[s] — no cv array.
__global__ __launch_bounds__(256) void k_combine_ln(const float* __restrict__ G,
                                                    const unsigned short* __restrict__ Gb,
                                                    const float* __restrict__ Ax,
                                                    const float* __restrict__ En,
                                                    const float* __restrict__ dego,
                                                    const int* __restrict__ off_d,
                                                    const int* __restrict__ idx_d,
                                                    const float* __restrict__ gamma,
                                                    const float* __restrict__ beta,
                                                    float* __restrict__ Xout, int n) {
  __shared__ float s4[4];
  const int t = threadIdx.x;
  // ---- softmax statistics prologue ----
  float mloc = -3.0e38f;
  for (int k = t; k < n; k += 256) mloc = fmaxf(mloc, En[k]);
  const float m = blkred(mloc, true, s4);
  const float invden = -1.0f / ((m + 1e-12f) * TEMP_);   // li = En*invden
  float se = 0.f, sl = 0.f;
  for (int k = t; k < n; k += 256) {
    float li = En[k] * invden;
    float e = __expf(li);
    se += e; sl += e * li;
  }
  se = blkred(se, false, s4);
  sl = blkred(sl, false, s4);
  const float logZ = __logf(se);
  const float S = logZ - sl / se;
  const float cmul = (1.0f / se) * (1.0f / TEMP_);
  const float cadd = S - logZ;
  // c(s) = expf(En[s]*invden) * cmul * (En[s]*invden + cadd)

  const int lane = t & 31;
  const int i = blockIdx.x * 8 + (t >> 5);
  const ushort4* Gv = (const ushort4*)Gb;
  const float4 gi = ((const float4*)G)[i * 32 + lane];
  float4 tf = make_float4(0.f, 0.f, 0.f, 0.f);
  float atc = 0.f;
  int o = off_d[i];
  const int oe = off_d[i + 1];
  for (; o + 4 <= oe; o += 4) {
    int s0 = idx_d[o], s1 = idx_d[o + 1], s2 = idx_d[o + 2], s3 = idx_d[o + 3];
    ushort4 r0 = Gv[s0 * 32 + lane], r1 = Gv[s1 * 32 + lane];
    ushort4 r2 = Gv[s2 * 32 + lane], r3 = Gv[s3 * 32 + lane];
    float l0 = En[s0] * invden, l1 = En[s1] * invden;
    float l2 = En[s2] * invden, l3 = En[s3] * invden;
    float c0 = __expf(l0) * cmul * (l0 + cadd);
    float c1 = __expf(l1) * cmul * (l1 + cadd);
    float c2 = __expf(l2) * cmul * (l2 + cadd);
    float c3 = __expf(l3) * cmul * (l3 + cadd);
    atc += (c0 + c1) + (c2 + c3);
    tf = f4_fma(c0, us4f4(r0), tf); tf = f4_fma(c1, us4f4(r1), tf);
    tf = f4_fma(c2, us4f4(r2), tf); tf = f4_fma(c3, us4f4(r3), tf);
  }
  for (; o < oe; ++o) {
    int s = idx_d[o];
    float ls = En[s] * invden;
    float cs = __expf(ls) * cmul * (ls + cadd);
    atc += cs;
    tf = f4_fma(cs, us4f4(Gv[s * 32 + lane]), tf);
  }
  const float li_i = En[i] * invden;
  const float ci = __expf(li_i) * cmul * (li_i + cadd);
  const float dg = dego[i];
  const float4 axi = ((const float4*)Ax)[i * 32 + lane];
  float4 v;
  v.x = fmaxf(gi.x + ci * (dg * gi.x - axi.x) + atc * gi.x - tf.x, 0.f);
  v.y = fmaxf(gi.y + ci * (dg * gi.y - axi.y) + atc * gi.y - tf.y, 0.f);
  v.z = fmaxf(gi.z + ci * (dg * gi.z - axi.z) + atc * gi.z - tf.z, 0.f);
  v.w = fmaxf(gi.w + ci * (dg * gi.w - axi.w) + atc * gi.w - tf.w, 0.f);
  float mu = grp_sum32(f4_hsum(v)) * (1.f / 128.f);
  float4 dv;
  dv.x = v.x - mu; dv.y = v.y - mu; dv.z = v.z - mu; dv.w = v.w - mu;
  float var = grp_sum32(dv.x * dv.x + dv.y * dv.y + dv.z * dv.z + dv.w * dv.w) * (1.f / 128.f);
  float rs = rsqrtf(var + LN_EPS_);
  float4 ga = ((const float4*)gamma)[lane];
  float4 be = ((const float4*)beta)[lane];
  float4 out;
  out.x = fmaf(dv.x * rs, ga.x, be.x);
  out.y = fmaf(dv.y * rs, ga.y, be.y);
  out.z = fmaf(dv.z * rs, ga.z, be.z);
  out.w = fmaf(dv.w * rs, ga.w, be.w);
  ((float4*)Xout)[i * 32 + lane] = out;
}

// ------- final conv aggregate (DOUT=64, bf16 rows): 16 lanes/node ----------
__global__ __launch_bounds__(256) void k_final_agg(const unsigned short* __restrict__ Hb,
                                                   const float* __restrict__ dinv,
                                                   const float* __restrict__ bout,
                                                   const int* __restrict__ off_d,
                                                   const int* __restrict__ idx_d,
                                                   float* __restrict__ out) {
  const int lane = threadIdx.x & 15;
  const int i = blockIdx.x * 16 + (threadIdx.x >> 4);
  const ushort4* Hv = (const ushort4*)Hb;
  const float di = dinv[i];
  float4 acc = us4f4(Hv[i * 16 + lane]);
  acc.x *= di; acc.y *= di; acc.z *= di; acc.w *= di;
  int o = off_d[i];
  const int oe = off_d[i + 1];
  for (; o + 4 <= oe; o += 4) {
    int s0 = idx_d[o], s1 = idx_d[o + 1], s2 = idx_d[o + 2], s3 = idx_d[o + 3];
    ushort4 r0 = Hv[s0 * 16 + lane], r1 = Hv[s1 * 16 + lane];
    ushort4 r2 = Hv[s2 * 16 + lane], r3 = Hv[s3 * 16 + lane];
    acc = f4_fma(dinv[s0], us4f4(r0), acc); acc = f4_fma(dinv[s1], us4f4(r1), acc);
    acc = f4_fma(dinv[s2], us4f4(r2), acc); acc = f4_fma(dinv[s3], us4f4(r3), acc);
  }
  for (; o < oe; ++o) {
    int s = idx_d[o];
    acc = f4_fma(dinv[s], us4f4(Hv[s * 16 + lane]), acc);
  }
  float4 bb = ((const float4*)bout)[lane];
  float4 r;
  r.x = fmaf(di, acc.x, bb.x); r.y = fmaf(di, acc.y, bb.y);
  r.z = fmaf(di, acc.z, bb.z); r.w = fmaf(di, acc.w, bb.w);
  ((float4*)out)[i * 16 + lane] = r;
}

extern "C" void kernel_launch(void* const* d_in, const int* in_sizes, int n_in,
                              void* d_out, int out_size, void* d_ws, size_t ws_size,
                              hipStream_t stream) {
  const float* x    = (const float*)d_in[0];
  const int*   ei   = (const int*)d_in[1];
  const float* W1   = (const float*)d_in[2];
  const float* b1   = (const float*)d_in[3];
  const float* W2   = (const float*)d_in[4];
  const float* b2   = (const float*)d_in[5];
  const float* Wout = (const float*)d_in[6];
  const float* bout = (const float*)d_in[7];
  const float* gam  = (const float*)d_in[8];
  const float* bet  = (const float*)d_in[9];
  float* out = (float*)d_out;

  const int N = in_sizes[0] / DH;   // 8000
  const int E = in_sizes[1] / 2;    // 256000

  float* ws = (float*)d_ws;
  float* xf = ws;   ws += N * DH;
  float* G  = ws;   ws += N * DH;
  float* Ax = ws;   ws += N * DH;
  float* sq = ws;   ws += N;
  float* En = ws;   ws += N;
  float* dinv = ws; ws += N;
  float* dego = ws; ws += N;
  unsigned short* Hb = (unsigned short*)ws; ws += N * DH / 2;   // bf16 N x 128
  unsigned short* Gb = (unsigned short*)ws; ws += N * DH / 2;   // bf16 N x 128
  int* cnt_d = (int*)ws; ws += N;
  int* cnt_s = (int*)ws; ws += N;
  int* off_d = (int*)ws; ws += N + 4;
  int* off_s = (int*)ws; ws += N + 4;
  int* idx_d = (int*)ws; ws += E;
  int* idx_s = (int*)ws; ws += E;

  const int NT = N / 16;            // 500 gemm tile blocks

  hipMemsetAsync(cnt_d, 0, 2 * N * sizeof(int), stream);  // cnt_d, cnt_s
  k_gemm1_hist<<<NT + 256, 256, 0, stream>>>(x, W1, Hb, ei, E, cnt_d, cnt_s, NT);
  k_scan<<<2, 1024, 0, stream>>>(cnt_d, cnt_s, off_d, off_s, dinv, dego, N);
  k_fill<<<(E + 255) / 256, 256, 0, stream>>>(ei, E, off_d, off_s, cnt_d, cnt_s,
                                              idx_d, idx_s);

  for (int l = 0; l < 2; ++l) {
    if (l) k_gemm<DH><<<N / 16, 256, 0, stream>>>(xf, W2, Hb);
    k_conv_agg<<<N / 8, 256, 0, stream>>>(Hb, dinv, l ? b2 : b1, off_d, idx_d,
                                          G, Gb, sq);
    k_ax_en<<<N / 8, 256, 0, stream>>>(G, Gb, sq, dego, off_s, idx_s, Ax, En);
    k_combine_ln<<<N / 8, 256, 0, stream>>>(G, Gb, Ax, En, dego, off_d, idx_d,
                                            gam, bet, xf, N);
  }
  k_gemm<64><<<N / 16, 256, 0, stream>>>(xf, Wout, Hb);
  k_final_agg<<<N / 16, 256, 0, stream>>>(Hb, dinv, bout, off_d, idx_d, out);
}

// Round 8
// 262.954 us; speedup vs baseline: 1.4753x; 1.0312x over previous
//
#include <hip/hip_runtime.h>
#include <hip/hip_bf16.h>

#define DH 128

static constexpr float TEMP_ = 10.0f;
static constexpr float LN_EPS_ = 1e-5f;

// ---------------- bf16 helpers ----------------
__device__ __forceinline__ unsigned short f2bf(float f) {
  union { float f; unsigned int i; } v; v.f = f;
  unsigned int b = v.i + 0x7FFFu + ((v.i >> 16) & 1u);   // RNE
  return (unsigned short)(b >> 16);
}
__device__ __forceinline__ void dec2(unsigned int u, float& lo, float& hi) {
  union { unsigned int i; float f; } a, b;
  a.i = u << 16; b.i = u & 0xFFFF0000u;
  lo = a.f; hi = b.f;
}
__device__ __forceinline__ void dec8(uint4 u, float* o) {
  dec2(u.x, o[0], o[1]); dec2(u.y, o[2], o[3]);
  dec2(u.z, o[4], o[5]); dec2(u.w, o[6], o[7]);
}
__device__ __forceinline__ unsigned int pack2(float lo, float hi) {
  return (unsigned int)f2bf(lo) | ((unsigned int)f2bf(hi) << 16);
}

__device__ __forceinline__ float grp_sum16(float v) {
  #pragma unroll
  for (int o = 8; o > 0; o >>= 1) v += __shfl_down(v, o, 16);
  return __shfl(v, 0, 16);
}

// 256-thread block reduce; s4 = 4-float LDS scratch. Returns to all threads.
__device__ __forceinline__ float blkred(float v, bool mx, float* s4) {
  const int t = threadIdx.x;
  #pragma unroll
  for (int o = 32; o > 0; o >>= 1) {
    float u = __shfl_down(v, o, 64);
    v = mx ? fmaxf(v, u) : v + u;
  }
  __syncthreads();
  if ((t & 63) == 0) s4[t >> 6] = v;
  __syncthreads();
  float r = mx ? fmaxf(fmaxf(s4[0], s4[1]), fmaxf(s4[2], s4[3]))
               : (s4[0] + s4[1]) + (s4[2] + s4[3]);
  __syncthreads();
  return r;
}

// ---------- fused: layer-1 GEMM (blocks < NT) + degree histogram ----------
__global__ __launch_bounds__(256) void k_gemm1_hist(const float* __restrict__ X,
                                                    const float* __restrict__ W,
                                                    unsigned short* __restrict__ Hb,
                                                    const int* __restrict__ ei, int E,
                                                    int* cnt_d, int* cnt_s, int NT) {
  __shared__ float Ws[64 * DH];
  __shared__ float xs[16 * 128];
  const int t = threadIdx.x;
  if ((int)blockIdx.x < NT) {
    const int row0 = blockIdx.x * 16;
    const float4* xg = (const float4*)(X + row0 * 128);
    float4* xs4 = (float4*)xs;
    xs4[t] = xg[t];
    xs4[t + 256] = xg[t + 256];
    const int c = t & 127, rg = t >> 7;   // RPT = 8
    float acc[8];
    #pragma unroll
    for (int r = 0; r < 8; ++r) acc[r] = 0.f;
    for (int kt = 0; kt < 2; ++kt) {
      __syncthreads();
      for (int i = t; i < 64 * DH; i += 256) Ws[i] = W[kt * 64 * DH + i];
      __syncthreads();
      for (int k = 0; k < 64; ++k) {
        float wv = Ws[k * DH + c];
        #pragma unroll
        for (int r = 0; r < 8; ++r)
          acc[r] += xs[(rg * 8 + r) * 128 + kt * 64 + k] * wv;
      }
    }
    #pragma unroll
    for (int r = 0; r < 8; ++r)
      Hb[(row0 + rg * 8 + r) * DH + c] = f2bf(acc[r]);
  } else {
    const int nb = gridDim.x - NT;
    for (int e = (blockIdx.x - NT) * 256 + t; e < E; e += nb * 256) {
      atomicAdd(&cnt_s[ei[e]], 1);
      atomicAdd(&cnt_d[ei[E + e]], 1);
    }
  }
}

// ------- GEMM: Hb[n,DOUT](bf16) = X[n,128](fp32) @ W[128,DOUT] -------------
template <int DOUT>
__global__ __launch_bounds__(256) void k_gemm(const float* __restrict__ X,
                                              const float* __restrict__ W,
                                              unsigned short* __restrict__ Hb) {
  __shared__ float Ws[64 * DOUT];
  __shared__ float xs[16 * 128];
  const int t = threadIdx.x;
  const int row0 = blockIdx.x * 16;

  const float4* xg = (const float4*)(X + row0 * 128);
  float4* xs4 = (float4*)xs;
  xs4[t] = xg[t];
  xs4[t + 256] = xg[t + 256];

  constexpr int RPT = (16 * DOUT) / 256;
  const int c = t % DOUT;
  const int rg = t / DOUT;
  float acc[RPT];
  #pragma unroll
  for (int r = 0; r < RPT; ++r) acc[r] = 0.f;

  for (int kt = 0; kt < 2; ++kt) {
    __syncthreads();
    for (int i = t; i < 64 * DOUT; i += 256) Ws[i] = W[kt * 64 * DOUT + i];
    __syncthreads();
    for (int k = 0; k < 64; ++k) {
      float wv = Ws[k * DOUT + c];
      #pragma unroll
      for (int r = 0; r < RPT; ++r)
        acc[r] += xs[(rg * RPT + r) * 128 + kt * 64 + k] * wv;
    }
  }
  #pragma unroll
  for (int r = 0; r < RPT; ++r)
    Hb[(row0 + rg * RPT + r) * DOUT + c] = f2bf(acc[r]);
}

// grid = 2: block 0 scans cnt_d -> off_d/dinv, block 1 scans cnt_s -> off_s/dego
__global__ __launch_bounds__(1024) void k_scan(int* cnt_d, int* cnt_s,
                                               int* off_d, int* off_s,
                                               float* dinv, float* dego, int n) {
  __shared__ int sm[1024];
  const int t = threadIdx.x;
  const int pass = blockIdx.x;
  int* cnt = pass ? cnt_s : cnt_d;
  int* off = pass ? off_s : off_d;
  const int base = t * 8;
  int lc[8]; int s = 0;
  #pragma unroll
  for (int j = 0; j < 8; ++j) {
    int idx = base + j;
    int v = (idx < n) ? cnt[idx] : 0;
    lc[j] = v; s += v;
  }
  sm[t] = s; __syncthreads();
  for (int o = 1; o < 1024; o <<= 1) {
    int v = (t >= o) ? sm[t - o] : 0;
    __syncthreads();
    sm[t] += v;
    __syncthreads();
  }
  int run = sm[t] - s;
  int total = sm[1023];
  #pragma unroll
  for (int j = 0; j < 8; ++j) {
    int idx = base + j;
    if (idx < n) {
      off[idx] = run; run += lc[j];
      if (pass == 0) dinv[idx] = rsqrtf((float)lc[j] + 1.0f);
      else           dego[idx] = (float)lc[j];
      cnt[idx] = 0;
    }
  }
  if (t == 0) off[n] = total;
}

__global__ void k_fill(const int* __restrict__ ei, int E,
                       const int* __restrict__ off_d, const int* __restrict__ off_s,
                       int* cnt_d, int* cnt_s, int* idx_d, int* idx_s) {
  int e = blockIdx.x * blockDim.x + threadIdx.x;
  if (e < E) {
    int s = ei[e], d = ei[E + e];
    int p = atomicAdd(&cnt_d[d], 1);
    idx_d[off_d[d] + p] = s;
    int q = atomicAdd(&cnt_s[s], 1);
    idx_s[off_s[s] + q] = d;
  }
}

// ------- conv aggregate: 16 lanes/node, uint4 (8 bf16) per lane -----------
// grid = N/16 blocks of 256 (16 groups/block).
__global__ __launch_bounds__(256) void k_conv_agg(const unsigned short* __restrict__ Hb,
                                                  const float* __restrict__ dinv,
                                                  const float* __restrict__ b,
                                                  const int* __restrict__ off_d,
                                                  const int* __restrict__ idx_d,
                                                  float* __restrict__ G,
                                                  unsigned short* __restrict__ Gb,
                                                  float* __restrict__ sq) {
  const int lane = threadIdx.x & 15;
  const int i = blockIdx.x * 16 + (threadIdx.x >> 4);
  const uint4* Hv = (const uint4*)Hb;
  const float di = dinv[i];
  float acc[8];
  {
    float t8[8]; dec8(Hv[i * 16 + lane], t8);
    #pragma unroll
    for (int k = 0; k < 8; ++k) acc[k] = di * t8[k];   // self loop
  }
  int o = off_d[i];
  const int oe = off_d[i + 1];
  for (; o + 8 <= oe; o += 8) {
    int s[8]; float dv[8]; uint4 r[8];
    #pragma unroll
    for (int j = 0; j < 8; ++j) s[j] = idx_d[o + j];
    #pragma unroll
    for (int j = 0; j < 8; ++j) { r[j] = Hv[s[j] * 16 + lane]; dv[j] = dinv[s[j]]; }
    #pragma unroll
    for (int j = 0; j < 8; ++j) {
      float t8[8]; dec8(r[j], t8);
      #pragma unroll
      for (int k = 0; k < 8; ++k) acc[k] = fmaf(dv[j], t8[k], acc[k]);
    }
  }
  for (; o < oe; ++o) {
    int s = idx_d[o];
    float dvs = dinv[s];
    float t8[8]; dec8(Hv[s * 16 + lane], t8);
    #pragma unroll
    for (int k = 0; k < 8; ++k) acc[k] = fmaf(dvs, t8[k], acc[k]);
  }
  const float4 b0 = ((const float4*)b)[lane * 2];
  const float4 b1 = ((const float4*)b)[lane * 2 + 1];
  float gi[8];
  gi[0] = fmaf(di, acc[0], b0.x); gi[1] = fmaf(di, acc[1], b0.y);
  gi[2] = fmaf(di, acc[2], b0.z); gi[3] = fmaf(di, acc[3], b0.w);
  gi[4] = fmaf(di, acc[4], b1.x); gi[5] = fmaf(di, acc[5], b1.y);
  gi[6] = fmaf(di, acc[6], b1.z); gi[7] = fmaf(di, acc[7], b1.w);
  ((float4*)G)[i * 32 + lane * 2]     = make_float4(gi[0], gi[1], gi[2], gi[3]);
  ((float4*)G)[i * 32 + lane * 2 + 1] = make_float4(gi[4], gi[5], gi[6], gi[7]);
  uint4 gp;
  gp.x = pack2(gi[0], gi[1]); gp.y = pack2(gi[2], gi[3]);
  gp.z = pack2(gi[4], gi[5]); gp.w = pack2(gi[6], gi[7]);
  ((uint4*)Gb)[i * 16 + lane] = gp;
  float s2 = 0.f;
  #pragma unroll
  for (int k = 0; k < 8; ++k) s2 += gi[k] * gi[k];
  s2 = grp_sum16(s2);
  if (lane == 0) sq[i] = s2;
}

// ------- Ax = A@G (CSR_src), Asq, En -------------------------------------
__global__ __launch_bounds__(256) void k_ax_en(const float* __restrict__ G,
                                               const unsigned short* __restrict__ Gb,
                                               const float* __restrict__ sq,
                                               const float* __restrict__ dego,
                                               const int* __restrict__ off_s,
                                               const int* __restrict__ idx_s,
                                               float* __restrict__ Ax,
                                               float* __restrict__ En) {
  const int lane = threadIdx.x & 15;
  const int i = blockIdx.x * 16 + (threadIdx.x >> 4);
  const uint4* Gv = (const uint4*)Gb;
  float axf[8];
  #pragma unroll
  for (int k = 0; k < 8; ++k) axf[k] = 0.f;
  float asq = 0.f;
  int o = off_s[i];
  const int oe = off_s[i + 1];
  for (; o + 8 <= oe; o += 8) {
    int s[8]; float qv[8]; uint4 r[8];
    #pragma unroll
    for (int j = 0; j < 8; ++j) s[j] = idx_s[o + j];
    #pragma unroll
    for (int j = 0; j < 8; ++j) { r[j] = Gv[s[j] * 16 + lane]; qv[j] = sq[s[j]]; }
    #pragma unroll
    for (int j = 0; j < 8; ++j) {
      float t8[8]; dec8(r[j], t8);
      asq += qv[j];
      #pragma unroll
      for (int k = 0; k < 8; ++k) axf[k] += t8[k];
    }
  }
  for (; o < oe; ++o) {
    int s = idx_s[o];
    float t8[8]; dec8(Gv[s * 16 + lane], t8);
    asq += sq[s];
    #pragma unroll
    for (int k = 0; k < 8; ++k) axf[k] += t8[k];
  }
  ((float4*)Ax)[i * 32 + lane * 2]     = make_float4(axf[0], axf[1], axf[2], axf[3]);
  ((float4*)Ax)[i * 32 + lane * 2 + 1] = make_float4(axf[4], axf[5], axf[6], axf[7]);
  const float4 g0 = ((const float4*)G)[i * 32 + lane * 2];
  const float4 g1 = ((const float4*)G)[i * 32 + lane * 2 + 1];
  float dot = g0.x * axf[0] + g0.y * axf[1] + g0.z * axf[2] + g0.w * axf[3]
            + g1.x * axf[4] + g1.y * axf[5] + g1.z * axf[6] + g1.w * axf[7];
  dot = grp_sum16(dot);
  if (lane == 0) En[i] = 0.5f * (dego[i] * sq[i] + asq - 2.f * dot);
}

// ------- combine: inline softmax stats + A^T c, A^T(c*g), eg, relu, LN -----
__global__ __launch_bounds__(256) void k_combine_ln(const float* __restrict__ G,
                                                    const unsigned short* __restrict__ Gb,
                                                    const float* __restrict__ Ax,
                                                    const float* __restrict__ En,
                                                    const float* __restrict__ dego,
                                                    const int* __restrict__ off_d,
                                                    const int* __restrict__ idx_d,
                                                    const float* __restrict__ gamma,
                                                    const float* __restrict__ beta,
                                                    float* __restrict__ Xout, int n) {
  __shared__ float s4[4];
  const int t = threadIdx.x;
  // ---- softmax statistics prologue (identical in every block) ----
  float mloc = -3.0e38f;
  for (int k = t; k < n; k += 256) mloc = fmaxf(mloc, En[k]);
  const float m = blkred(mloc, true, s4);
  const float invden = -1.0f / ((m + 1e-12f) * TEMP_);   // li = En*invden
  float se = 0.f, sl = 0.f;
  for (int k = t; k < n; k += 256) {
    float li = En[k] * invden;
    float e = __expf(li);
    se += e; sl += e * li;
  }
  se = blkred(se, false, s4);
  sl = blkred(sl, false, s4);
  const float logZ = __logf(se);
  const float S = logZ - sl / se;
  const float cmul = (1.0f / se) * (1.0f / TEMP_);
  const float cadd = S - logZ;
  // c(s) = __expf(En[s]*invden) * cmul * (En[s]*invden + cadd)

  const int lane = t & 15;
  const int i = blockIdx.x * 16 + (t >> 4);
  const uint4* Gv = (const uint4*)Gb;
  const float4 g0 = ((const float4*)G)[i * 32 + lane * 2];
  const float4 g1 = ((const float4*)G)[i * 32 + lane * 2 + 1];
  const float gi[8] = { g0.x, g0.y, g0.z, g0.w, g1.x, g1.y, g1.z, g1.w };
  float tf[8];
  #pragma unroll
  for (int k = 0; k < 8; ++k) tf[k] = 0.f;
  float atc = 0.f;
  int o = off_d[i];
  const int oe = off_d[i + 1];
  for (; o + 8 <= oe; o += 8) {
    int s[8]; float ev[8]; uint4 r[8];
    #pragma unroll
    for (int j = 0; j < 8; ++j) s[j] = idx_d[o + j];
    #pragma unroll
    for (int j = 0; j < 8; ++j) { r[j] = Gv[s[j] * 16 + lane]; ev[j] = En[s[j]]; }
    #pragma unroll
    for (int j = 0; j < 8; ++j) {
      float ls = ev[j] * invden;
      float cs = __expf(ls) * cmul * (ls + cadd);
      atc += cs;
      float t8[8]; dec8(r[j], t8);
      #pragma unroll
      for (int k = 0; k < 8; ++k) tf[k] = fmaf(cs, t8[k], tf[k]);
    }
  }
  for (; o < oe; ++o) {
    int s = idx_d[o];
    float ls = En[s] * invden;
    float cs = __expf(ls) * cmul * (ls + cadd);
    atc += cs;
    float t8[8]; dec8(Gv[s * 16 + lane], t8);
    #pragma unroll
    for (int k = 0; k < 8; ++k) tf[k] = fmaf(cs, t8[k], tf[k]);
  }
  const float li_i = En[i] * invden;
  const float ci = __expf(li_i) * cmul * (li_i + cadd);
  const float dg = dego[i];
  const float4 a0 = ((const float4*)Ax)[i * 32 + lane * 2];
  const float4 a1 = ((const float4*)Ax)[i * 32 + lane * 2 + 1];
  const float axi[8] = { a0.x, a0.y, a0.z, a0.w, a1.x, a1.y, a1.z, a1.w };
  float v[8];
  float ssum = 0.f;
  #pragma unroll
  for (int k = 0; k < 8; ++k) {
    v[k] = fmaxf(gi[k] + ci * (dg * gi[k] - axi[k]) + atc * gi[k] - tf[k], 0.f);
    ssum += v[k];
  }
  float mu = grp_sum16(ssum) * (1.f / 128.f);
  float vsum = 0.f;
  #pragma unroll
  for (int k = 0; k < 8; ++k) {
    v[k] -= mu;
    vsum += v[k] * v[k];
  }
  float var = grp_sum16(vsum) * (1.f / 128.f);
  float rs = rsqrtf(var + LN_EPS_);
  const float4 ga0 = ((const float4*)gamma)[lane * 2];
  const float4 ga1 = ((const float4*)gamma)[lane * 2 + 1];
  const float4 be0 = ((const float4*)beta)[lane * 2];
  const float4 be1 = ((const float4*)beta)[lane * 2 + 1];
  float4 o0, o1;
  o0.x = fmaf(v[0] * rs, ga0.x, be0.x); o0.y = fmaf(v[1] * rs, ga0.y, be0.y);
  o0.z = fmaf(v[2] * rs, ga0.z, be0.z); o0.w = fmaf(v[3] * rs, ga0.w, be0.w);
  o1.x = fmaf(v[4] * rs, ga1.x, be1.x); o1.y = fmaf(v[5] * rs, ga1.y, be1.y);
  o1.z = fmaf(v[6] * rs, ga1.z, be1.z); o1.w = fmaf(v[7] * rs, ga1.w, be1.w);
  ((float4*)Xout)[i * 32 + lane * 2]     = o0;
  ((float4*)Xout)[i * 32 + lane * 2 + 1] = o1;
}

// ------- final conv aggregate (DOUT=64, bf16 rows): 8 lanes/node -----------
// grid = N/32 blocks of 256 (32 groups/block).
__global__ __launch_bounds__(256) void k_final_agg(const unsigned short* __restrict__ Hb,
                                                   const float* __restrict__ dinv,
                                                   const float* __restrict__ bout,
                                                   const int* __restrict__ off_d,
                                                   const int* __restrict__ idx_d,
                                                   float* __restrict__ out) {
  const int lane = threadIdx.x & 7;
  const int i = blockIdx.x * 32 + (threadIdx.x >> 3);
  const uint4* Hv = (const uint4*)Hb;
  const float di = dinv[i];
  float acc[8];
  {
    float t8[8]; dec8(Hv[i * 8 + lane], t8);
    #pragma unroll
    for (int k = 0; k < 8; ++k) acc[k] = di * t8[k];
  }
  int o = off_d[i];
  const int oe = off_d[i + 1];
  for (; o + 8 <= oe; o += 8) {
    int s[8]; float dv[8]; uint4 r[8];
    #pragma unroll
    for (int j = 0; j < 8; ++j) s[j] = idx_d[o + j];
    #pragma unroll
    for (int j = 0; j < 8; ++j) { r[j] = Hv[s[j] * 8 + lane]; dv[j] = dinv[s[j]]; }
    #pragma unroll
    for (int j = 0; j < 8; ++j) {
      float t8[8]; dec8(r[j], t8);
      #pragma unroll
      for (int k = 0; k < 8; ++k) acc[k] = fmaf(dv[j], t8[k], acc[k]);
    }
  }
  for (; o < oe; ++o) {
    int s = idx_d[o];
    float dvs = dinv[s];
    float t8[8]; dec8(Hv[s * 8 + lane], t8);
    #pragma unroll
    for (int k = 0; k < 8; ++k) acc[k] = fmaf(dvs, t8[k], acc[k]);
  }
  const float4 b0 = ((const float4*)bout)[lane * 2];
  const float4 b1 = ((const float4*)bout)[lane * 2 + 1];
  float4 r0, r1;
  r0.x = fmaf(di, acc[0], b0.x); r0.y = fmaf(di, acc[1], b0.y);
  r0.z = fmaf(di, acc[2], b0.z); r0.w = fmaf(di, acc[3], b0.w);
  r1.x = fmaf(di, acc[4], b1.x); r1.y = fmaf(di, acc[5], b1.y);
  r1.z = fmaf(di, acc[6], b1.z); r1.w = fmaf(di, acc[7], b1.w);
  ((float4*)out)[i * 16 + lane * 2]     = r0;
  ((float4*)out)[i * 16 + lane * 2 + 1] = r1;
}

extern "C" void kernel_launch(void* const* d_in, const int* in_sizes, int n_in,
                              void* d_out, int out_size, void* d_ws, size_t ws_size,
                              hipStream_t stream) {
  const float* x    = (const float*)d_in[0];
  const int*   ei   = (const int*)d_in[1];
  const float* W1   = (const float*)d_in[2];
  const float* b1   = (const float*)d_in[3];
  const float* W2   = (const float*)d_in[4];
  const float* b2   = (const float*)d_in[5];
  const float* Wout = (const float*)d_in[6];
  const float* bout = (const float*)d_in[7];
  const float* gam  = (const float*)d_in[8];
  const float* bet  = (const float*)d_in[9];
  float* out = (float*)d_out;

  const int N = in_sizes[0] / DH;   // 8000
  const int E = in_sizes[1] / 2;    // 256000

  float* ws = (float*)d_ws;
  float* xf = ws;   ws += N * DH;
  float* G  = ws;   ws += N * DH;
  float* Ax = ws;   ws += N * DH;
  float* sq = ws;   ws += N;
  float* En = ws;   ws += N;
  float* dinv = ws; ws += N;
  float* dego = ws; ws += N;
  unsigned short* Hb = (unsigned short*)ws; ws += N * DH / 2;   // bf16 N x 128
  unsigned short* Gb = (unsigned short*)ws; ws += N * DH / 2;   // bf16 N x 128
  int* cnt_d = (int*)ws; ws += N;
  int* cnt_s = (int*)ws; ws += N;
  int* off_d = (int*)ws; ws += N + 4;
  int* off_s = (int*)ws; ws += N + 4;
  int* idx_d = (int*)ws; ws += E;
  int* idx_s = (int*)ws; ws += E;

  const int NT = N / 16;            // 500 gemm tile blocks

  hipMemsetAsync(cnt_d, 0, 2 * N * sizeof(int), stream);  // cnt_d, cnt_s
  k_gemm1_hist<<<NT + 256, 256, 0, stream>>>(x, W1, Hb, ei, E, cnt_d, cnt_s, NT);
  k_scan<<<2, 1024, 0, stream>>>(cnt_d, cnt_s, off_d, off_s, dinv, dego, N);
  k_fill<<<(E + 255) / 256, 256, 0, stream>>>(ei, E, off_d, off_s, cnt_d, cnt_s,
                                              idx_d, idx_s);

  for (int l = 0; l < 2; ++l) {
    if (l) k_gemm<DH><<<N / 16, 256, 0, stream>>>(xf, W2, Hb);
    k_conv_agg<<<N / 16, 256, 0, stream>>>(Hb, dinv, l ? b2 : b1, off_d, idx_d,
                                           G, Gb, sq);
    k_ax_en<<<N / 16, 256, 0, stream>>>(G, Gb, sq, dego, off_s, idx_s, Ax, En);
    k_combine_ln<<<N / 16, 256, 0, stream>>>(G, Gb, Ax, En, dego, off_d, idx_d,
                                             gam, bet, xf, N);
  }
  k_gemm<64><<<N / 16, 256, 0, stream>>>(xf, Wout, Hb);
  k_final_agg<<<N / 32, 256, 0, stream>>>(Hb, dinv, bout, off_d, idx_d, out);
}